// Round 9
// baseline (579.100 us; speedup 1.0000x reference)
//
#include <hip/hip_runtime.h>
#include <hip/hip_bf16.h>

#define DM 512
#define DH 64
#define NH 8
#define NP 2048
#define NB 2
#define NROWS (NB*NP)
#define JC 8                 // j-chunks (chunk = 256 j = 16 jt of 16)
#define OPITCH 520           // LDS pitch (shorts)
#define SIG 256.0f
#define INVSIG (1.0f/256.0f)

typedef _Float16 f16x8 __attribute__((ext_vector_type(8)));
typedef _Float16 f16x4 __attribute__((ext_vector_type(4)));
typedef _Float16 f16x2 __attribute__((ext_vector_type(2)));
typedef __fp16 fp16x2_n __attribute__((ext_vector_type(2)));
typedef float f32x4 __attribute__((ext_vector_type(4)));
typedef unsigned int u32x4 __attribute__((ext_vector_type(4)));
typedef unsigned int u32x2 __attribute__((ext_vector_type(2)));
typedef unsigned int u32;

__device__ __forceinline__ f16x2 pkrtz(float a, float b){
  fp16x2_n r = __builtin_amdgcn_cvt_pkrtz(a, b);
  return __builtin_bit_cast(f16x2, r);
}

__device__ __forceinline__ f32x4 mfma_qk(f16x8 a, f16x8 b, f32x4 c){
  return __builtin_amdgcn_mfma_f32_16x16x32_f16(a, b, c, 0, 0, 0);
}

__device__ __forceinline__ f32x4 mfma_pv(f16x4 a, f16x4 b, f32x4 c){
  return __builtin_amdgcn_mfma_f32_16x16x16f16(a, b, c, 0, 0, 0);
}

// ---------------- prep: x fp32 -> fp16 ----------------
__global__ void prep_x(const float* __restrict__ x, unsigned short* __restrict__ xh){
  int i = (blockIdx.x*256 + threadIdx.x)*4;
  float4 v = *(const float4*)(x + i);
  f16x2 a = pkrtz(v.x, v.y), b = pkrtz(v.z, v.w);
  u32x2 u; u.x = __builtin_bit_cast(u32, a); u.y = __builtin_bit_cast(u32, b);
  *(u32x2*)(xh + i) = u;
}

// ---------------- prep: transpose weights to [n][k] fp16 ----------------
__global__ void prep_w(const float* __restrict__ Wq, const float* __restrict__ Wk,
                       const float* __restrict__ Wv, const float* __restrict__ Wp,
                       unsigned short* __restrict__ WT){
  __shared__ float t[64][65];
  const float* W = (blockIdx.z==0)?Wq:(blockIdx.z==1)?Wk:(blockIdx.z==2)?Wv:Wp;
  const int k0 = blockIdx.x*64, n0 = blockIdx.y*64;
  const int c = threadIdx.x&63, rq = threadIdx.x>>6;
  #pragma unroll
  for(int rr=0;rr<16;rr++){
    int kl = rq*16+rr;
    t[kl][c] = W[(size_t)(k0+kl)*DM + n0 + c];
  }
  __syncthreads();
  unsigned short* o = WT + (size_t)blockIdx.z*DM*DM;
  #pragma unroll
  for(int rr=0;rr<16;rr++){
    int nl = rq*16+rr;
    o[(size_t)(n0+nl)*DM + k0 + c] = __builtin_bit_cast(unsigned short, (_Float16)t[c][nl]);
  }
}

// ---------------- QKV projection GEMM (fp16) ----------------
// z=0: Qs (scaled 1/8) [b][h][p][d]; z=1: K [b][h][p][d];
// z=2: VA — V^T A-frag layout [b][g][nt][p/4][d&15][p&3]  (R6-verified layout)
__global__ __launch_bounds__(256) void qkv_kern(const unsigned short* __restrict__ xh,
    const unsigned short* __restrict__ WT,
    unsigned short* __restrict__ Qs, unsigned short* __restrict__ Kk,
    unsigned short* __restrict__ VA){
  const int z = blockIdx.z, h = blockIdx.y;
  const int R0 = blockIdx.x*64;
  const int tid = threadIdx.x;
  const int w = tid>>6, lane = tid&63, m = lane&15, q = lane>>4;
  const unsigned short* Wz = WT + (size_t)z*DM*DM;
  f32x4 acc[4] = {};
  const unsigned short* arow = xh + (size_t)(R0 + w*16 + m)*DM + q*8;
  const unsigned short* brow = Wz + (size_t)(h*64 + m)*DM + q*8;
  for(int k=0;k<DM;k+=32){
    f16x8 A = *(const f16x8*)(arow + k);
    #pragma unroll
    for(int nt=0;nt<4;nt++){
      f16x8 B = *(const f16x8*)(brow + (size_t)nt*16*DM + k);
      acc[nt] = mfma_qk(A, B, acc[nt]);
    }
  }
  __shared__ float t[64][65];
  const float scale = (z==0) ? 0.125f : 1.0f;
  #pragma unroll
  for(int nt=0;nt<4;nt++)
    #pragma unroll
    for(int r=0;r<4;r++)
      t[w*16 + q*4 + r][nt*16 + m] = acc[nt][r]*scale;
  __syncthreads();
  const int b = R0>>11, p0 = R0&2047;
  if(z<2){
    unsigned short* outp = (z==0)? Qs : Kk;
    int pl = tid>>2, c0 = (tid&3)*16;
    u32x4 u0, u1;
    u0.x=__builtin_bit_cast(u32, pkrtz(t[pl][c0+0], t[pl][c0+1]));
    u0.y=__builtin_bit_cast(u32, pkrtz(t[pl][c0+2], t[pl][c0+3]));
    u0.z=__builtin_bit_cast(u32, pkrtz(t[pl][c0+4], t[pl][c0+5]));
    u0.w=__builtin_bit_cast(u32, pkrtz(t[pl][c0+6], t[pl][c0+7]));
    u1.x=__builtin_bit_cast(u32, pkrtz(t[pl][c0+8], t[pl][c0+9]));
    u1.y=__builtin_bit_cast(u32, pkrtz(t[pl][c0+10],t[pl][c0+11]));
    u1.z=__builtin_bit_cast(u32, pkrtz(t[pl][c0+12],t[pl][c0+13]));
    u1.w=__builtin_bit_cast(u32, pkrtz(t[pl][c0+14],t[pl][c0+15]));
    unsigned short* dst = outp + ((size_t)(b*NH+h)*NP + p0+pl)*DH + c0;
    *(u32x4*)dst = u0; *(u32x4*)(dst+8) = u1;
  } else {
    int d = tid>>2, c0 = (tid&3)*16;
    unsigned short* vb = VA + (size_t)b*(8u*4u*(NP/4)*64u)
        + ((size_t)(h*4 + (d>>4))*(NP/4))*64 + (size_t)(d&15)*4;
    #pragma unroll
    for(int grp=0; grp<4; grp++){
      int pl = c0 + grp*4;
      u32x2 u;
      u.x = __builtin_bit_cast(u32, pkrtz(t[pl+0][d], t[pl+1][d]));
      u.y = __builtin_bit_cast(u32, pkrtz(t[pl+2][d], t[pl+3][d]));
      *(u32x2*)(vb + (size_t)((p0 + pl)>>2)*64) = u;
    }
  }
}

// ---------------- attn sweep 1: partial softmax denominators ----------------
// 128-thread blocks; pk-f16 mix1, exp2 (log2e folded into W1).
__global__ __launch_bounds__(128,2) void attn1_kern(const unsigned short* __restrict__ Qs,
    const unsigned short* __restrict__ Kk, const float* __restrict__ W1,
    float* __restrict__ Lpart){
  const int bx = blockIdx.x;
  const int c = bx & 7;
  const int b = (bx>>3) & 1;
  const int it = bx>>4;
  const int tid = threadIdx.x;
  const int iw = tid>>6, lane = tid&63, m = lane&15, q = lane>>4;
  const int i0 = it*32 + iw*16;
  const int cb = c*(NP/JC);

  f16x2 w1f[8][8];
  #pragma unroll
  for(int h=0;h<8;h++)
    #pragma unroll
    for(int g=0;g<8;g++){
      _Float16 v = (_Float16)(W1[h*8+g]*1.44269504f);
      f16x2 p; p[0]=v; p[1]=v; w1f[h][g]=p;
    }

  const unsigned short* Qb = Qs + (size_t)b*NH*NP*DH;
  const unsigned short* Kb = Kk + (size_t)b*NH*NP*DH;

  f16x8 Qf[8][2];
  #pragma unroll
  for(int h=0;h<8;h++){
    const unsigned short* qp = Qb + ((size_t)h*NP + i0 + m)*DH + q*8;
    Qf[h][0] = *(const f16x8*)(qp);
    Qf[h][1] = *(const f16x8*)(qp + 32);
  }

  float lacc[8] = {};
  for(int jt=0; jt<NP/JC/16; jt++){
    const int j0 = cb + jt*16;
    f16x8 K[8][2];
    #pragma unroll
    for(int h=0;h<8;h++){
      const unsigned short* kp = Kb + ((size_t)h*NP + j0 + m)*DH + q*8;
      K[h][0] = *(const f16x8*)(kp);
      K[h][1] = *(const f16x8*)(kp + 32);
    }
    f16x2 shl[8], shh[8];
    #pragma unroll
    for(int h=0;h<8;h++){
      f32x4 z = {};
      z = mfma_qk(K[h][0], Qf[h][0], z);     // A=K (m=j), B=Q (n=i) -> S^T
      f32x4 Sh = mfma_qk(K[h][1], Qf[h][1], z);
      shl[h] = pkrtz(Sh[0], Sh[1]);
      shh[h] = pkrtz(Sh[2], Sh[3]);
    }
    #pragma unroll
    for(int g=0;g<8;g++){
      f16x2 tl = shl[0]*w1f[0][g], th = shh[0]*w1f[0][g];
      #pragma unroll
      for(int h=1;h<8;h++){ tl += shl[h]*w1f[h][g]; th += shh[h]*w1f[h][g]; }
      float e0 = __builtin_amdgcn_exp2f((float)tl[0]);
      float e1 = __builtin_amdgcn_exp2f((float)tl[1]);
      float e2 = __builtin_amdgcn_exp2f((float)th[0]);
      float e3 = __builtin_amdgcn_exp2f((float)th[1]);
      lacc[g] += (e0+e1)+(e2+e3);
    }
  }
  #pragma unroll
  for(int g=0;g<8;g++){
    float v = lacc[g];
    v += __shfl_xor(v,16); v += __shfl_xor(v,32);
    lacc[g] = v;
  }
  if(lane < 16){
    #pragma unroll
    for(int g=0;g<8;g++)
      Lpart[(((size_t)c*NB + b)*NH + g)*NP + i0 + lane] = lacc[g];
  }
}

// ---------------- attn sweep 2: fused QK+mix1+exp2+mix2+PV (pk-f16) -------
// R6-verified structure: Q in LDS (wave-private rows), S^T C-layout feeds
// 16x16x16 PV MFMA directly as B-operand; sigma prescale vs f16 denorms.
__global__ __launch_bounds__(128,2) void attn2_kern(const unsigned short* __restrict__ Qs,
    const unsigned short* __restrict__ Kk, const unsigned short* __restrict__ VA,
    const float* __restrict__ W1, const float* __restrict__ W2,
    const float* __restrict__ Lpart, unsigned short* __restrict__ Opart){
  const int bx = blockIdx.x;
  const int c = bx & 7;
  const int b = (bx>>3) & 1;
  const int it = bx>>4;
  const int tid = threadIdx.x;
  const int iw = tid>>6, lane = tid&63, m = lane&15, q = lane>>4;
  const int i0 = it*32 + iw*16;
  const int cb = c*(NP/JC);

  __shared__ unsigned short Osh[32*OPITCH];

  f16x2 w1f[8][8], w2f[8][8];
  #pragma unroll
  for(int h=0;h<8;h++)
    #pragma unroll
    for(int g=0;g<8;g++){
      _Float16 v1 = (_Float16)(W1[h*8+g]*1.44269504f);
      _Float16 v2 = (_Float16)W2[h*8+g];
      f16x2 p1; p1[0]=v1; p1[1]=v1; w1f[h][g]=p1;
      f16x2 p2; p2[0]=v2; p2[1]=v2; w2f[h][g]=p2;
    }

  const unsigned short* Qb = Qs + (size_t)b*NH*NP*DH;
  const unsigned short* Kb = Kk + (size_t)b*NH*NP*DH;
  const unsigned short* VAb = VA + (size_t)b*(8u*4u*(NP/4)*64u);

  // stage this wave's 16 Q rows into its own LDS rows (wave-private, no barrier)
  {
    const int qr = lane>>2, qc = (lane&3)*16;
    #pragma unroll
    for(int h=0;h<8;h++){
      const unsigned short* src = Qb + ((size_t)h*NP + i0 + qr)*DH + qc;
      unsigned short* dst = &Osh[(size_t)(iw*16+qr)*OPITCH + h*64 + qc];
      *(u32x4*)dst = *(const u32x4*)src;
      *(u32x4*)(dst+8) = *(const u32x4*)(src+8);
    }
  }

  // sigma/l per softmax-head g for this lane's i (= i0 + m)
  float rl[8];
  #pragma unroll
  for(int g=0;g<8;g++){
    float v = 0.f;
    #pragma unroll
    for(int cc=0;cc<JC;cc++)
      v += Lpart[(((size_t)cc*NB + b)*NH + g)*NP + i0 + m];
    rl[g] = SIG/v;
  }

  f32x4 Oacc[8][4] = {};
  const unsigned short* QL = &Osh[(size_t)(iw*16+m)*OPITCH];

  for(int jt=0; jt<NP/JC/16; jt++){
    const int j0 = cb + jt*16;
    f16x8 K[8][2];
    #pragma unroll
    for(int h=0;h<8;h++){
      const unsigned short* kp = Kb + ((size_t)h*NP + j0 + m)*DH + q*8;
      K[h][0] = *(const f16x8*)(kp);
      K[h][1] = *(const f16x8*)(kp + 32);
    }
    // V fragments early (latency hidden behind QK+mix+exp)
    f16x4 Vf[8][4];
    const size_t jq = (size_t)(j0>>2) + q;
    #pragma unroll
    for(int g=0;g<8;g++)
      #pragma unroll
      for(int nt=0;nt<4;nt++)
        Vf[g][nt] = *(const f16x4*)(VAb + ((((size_t)g*4+nt)*(NP/4) + jq)<<6) + (m<<2));
    f16x2 shl[8], shh[8];
    #pragma unroll
    for(int h=0;h<8;h++){
      f16x8 q0 = *(const f16x8*)(QL + h*64 + q*8);
      f16x8 q1 = *(const f16x8*)(QL + h*64 + 32 + q*8);
      f32x4 z = {};
      z = mfma_qk(K[h][0], q0, z);
      f32x4 Sh = mfma_qk(K[h][1], q1, z);
      shl[h] = pkrtz(Sh[0], Sh[1]);
      shh[h] = pkrtz(Sh[2], Sh[3]);
    }
    // mix1 (pk) -> exp2 -> normalize+prescale -> P in f16 pairs
    f16x2 plo[8], phi[8];
    #pragma unroll
    for(int g=0;g<8;g++){
      f16x2 tl = shl[0]*w1f[0][g], th = shh[0]*w1f[0][g];
      #pragma unroll
      for(int h=1;h<8;h++){ tl += shl[h]*w1f[h][g]; th += shh[h]*w1f[h][g]; }
      float e0 = __builtin_amdgcn_exp2f((float)tl[0])*rl[g];
      float e1 = __builtin_amdgcn_exp2f((float)tl[1])*rl[g];
      float e2 = __builtin_amdgcn_exp2f((float)th[0])*rl[g];
      float e3 = __builtin_amdgcn_exp2f((float)th[1])*rl[g];
      plo[g] = pkrtz(e0, e1);
      phi[g] = pkrtz(e2, e3);
    }
    // mix2 (pk) -> A2 frag -> PV
    #pragma unroll
    for(int go=0; go<8; go++){
      f16x2 al = plo[0]*w2f[0][go], ah = phi[0]*w2f[0][go];
      #pragma unroll
      for(int h=1;h<8;h++){ al += plo[h]*w2f[h][go]; ah += phi[h]*w2f[h][go]; }
      u32x2 au; au.x = __builtin_bit_cast(u32, al); au.y = __builtin_bit_cast(u32, ah);
      f16x4 A2 = __builtin_bit_cast(f16x4, au);
      #pragma unroll
      for(int nt=0;nt<4;nt++)
        Oacc[go][nt] = mfma_pv(Vf[go][nt], A2, Oacc[go][nt]);
    }
  }

  // epilogue: unscale 1/sigma, wave-private LDS rows, coalesced stores
  #pragma unroll
  for(int g=0;g<8;g++)
    #pragma unroll
    for(int nt=0;nt<4;nt++){
      f32x4 o = Oacc[g][nt];
      u32x2 u;
      u.x = __builtin_bit_cast(u32, pkrtz(o[0]*INVSIG, o[1]*INVSIG));
      u.y = __builtin_bit_cast(u32, pkrtz(o[2]*INVSIG, o[3]*INVSIG));
      *(u32x2*)(&Osh[(size_t)(iw*16 + m)*OPITCH + g*64 + nt*16 + 4*q]) = u;
    }
  __syncthreads();
  unsigned short* Oc = Opart + (size_t)c*NROWS*DM;
  const size_t R0 = (size_t)b*NP + (size_t)it*32;
  #pragma unroll
  for(int t=0;t<16;t++){
    int idx = t*128 + tid;
    int row = idx>>6, c8 = idx&63;
    u32x4 v = *(const u32x4*)(&Osh[(size_t)row*OPITCH + c8*8]);
    __builtin_nontemporal_store(v, (u32x4*)(Oc + (R0 + row)*DM + c8*8));
  }
}

// ---------------- output projection: out = (sum_c Opart_c) @ Wproj --------
__global__ __launch_bounds__(256) void oproj_kern(const unsigned short* __restrict__ Opart,
    const unsigned short* __restrict__ WT, float* __restrict__ out){
  const int nb = blockIdx.y;
  const int R0 = blockIdx.x*64;
  const int tid = threadIdx.x;
  const int w = tid>>6, lane = tid&63, m = lane&15, q = lane>>4;
  const unsigned short* Wp = WT + (size_t)3*DM*DM;
  f32x4 acc[4] = {};
  const size_t rowoff = (size_t)(R0 + w*16 + m)*DM + q*8;
  const unsigned short* brow = Wp + (size_t)(nb*64 + m)*DM + q*8;
  for(int k=0;k<DM;k+=32){
    f16x8 A = *(const f16x8*)(Opart + rowoff + k);
    #pragma unroll
    for(int cc=1;cc<JC;cc++)
      A += *(const f16x8*)(Opart + (size_t)cc*NROWS*DM + rowoff + k);
    #pragma unroll
    for(int nt=0;nt<4;nt++){
      f16x8 B = *(const f16x8*)(brow + (size_t)nt*16*DM + k);
      acc[nt] = mfma_qk(A, B, acc[nt]);
    }
  }
  #pragma unroll
  for(int nt=0;nt<4;nt++)
    #pragma unroll
    for(int r=0;r<4;r++)
      out[(size_t)(R0 + w*16 + q*4 + r)*DM + nb*64 + nt*16 + m] = acc[nt][r];
}

extern "C" void kernel_launch(void* const* d_in, const int* in_sizes, int n_in,
                              void* d_out, int out_size, void* d_ws, size_t ws_size,
                              hipStream_t stream){
  (void)in_sizes; (void)n_in; (void)out_size; (void)ws_size;
  const float* x  = (const float*)d_in[0];
  const float* Wq = (const float*)d_in[1];
  const float* Wk = (const float*)d_in[2];
  const float* Wv = (const float*)d_in[3];
  const float* W1 = (const float*)d_in[4];
  const float* W2 = (const float*)d_in[5];
  const float* Wp = (const float*)d_in[6];

  char* ws = (char*)d_ws;
  unsigned short* xh = (unsigned short*)ws;  ws += (size_t)NROWS*DM*2;     // 4 MB
  unsigned short* WT = (unsigned short*)ws;  ws += (size_t)4*DM*DM*2;      // 2 MB
  unsigned short* Qs = (unsigned short*)ws;  ws += (size_t)NB*NH*NP*DH*2;  // 4 MB
  unsigned short* Kk = (unsigned short*)ws;  ws += (size_t)NB*NH*NP*DH*2;  // 4 MB
  unsigned short* VA = (unsigned short*)ws;  ws += (size_t)NB*NH*DH*NP*2;  // 4 MB
  float*          Lp = (float*)ws;           ws += (size_t)JC*NB*NH*NP*4;  // 1 MB
  unsigned short* Op = (unsigned short*)ws;  ws += (size_t)JC*NROWS*DM*2;  // 32 MB

  prep_x<<<NROWS*DM/1024, 256, 0, stream>>>(x, xh);
  prep_w<<<dim3(8,8,4), 256, 0, stream>>>(Wq, Wk, Wv, Wp, WT);
  qkv_kern<<<dim3(64,8,3), 256, 0, stream>>>(xh, WT, Qs, Kk, VA);
  attn1_kern<<<dim3(1024), 128, 0, stream>>>(Qs, Kk, W1, Lp);
  attn2_kern<<<dim3(1024), 128, 0, stream>>>(Qs, Kk, VA, W1, W2, Lp, Op);
  oproj_kern<<<dim3(64,8), 256, 0, stream>>>(Op, WT, (float*)d_out);
}

// Round 10
// 576.107 us; speedup vs baseline: 1.0052x; 1.0052x over previous
//
#include <hip/hip_runtime.h>
#include <hip/hip_bf16.h>

#define DM 512
#define DH 64
#define NH 8
#define NP 2048
#define NB 2
#define NROWS (NB*NP)
#define JC 8                 // j-chunks (chunk = 256 j = 16 jt of 16)
#define OPITCH 520           // LDS pitch (shorts)
#define SIG 256.0f
#define INVSIG (1.0f/256.0f)

typedef _Float16 f16x8 __attribute__((ext_vector_type(8)));
typedef _Float16 f16x4 __attribute__((ext_vector_type(4)));
typedef _Float16 f16x2 __attribute__((ext_vector_type(2)));
typedef __fp16 fp16x2_n __attribute__((ext_vector_type(2)));
typedef float f32x4 __attribute__((ext_vector_type(4)));
typedef unsigned int u32x4 __attribute__((ext_vector_type(4)));
typedef unsigned int u32x2 __attribute__((ext_vector_type(2)));
typedef unsigned int u32;

__device__ __forceinline__ f16x2 pkrtz(float a, float b){
  fp16x2_n r = __builtin_amdgcn_cvt_pkrtz(a, b);
  return __builtin_bit_cast(f16x2, r);
}

__device__ __forceinline__ f32x4 mfma_qk(f16x8 a, f16x8 b, f32x4 c){
  return __builtin_amdgcn_mfma_f32_16x16x32_f16(a, b, c, 0, 0, 0);
}

__device__ __forceinline__ f32x4 mfma_pv(f16x4 a, f16x4 b, f32x4 c){
  return __builtin_amdgcn_mfma_f32_16x16x16f16(a, b, c, 0, 0, 0);
}

// ---------------- prep: x fp32 -> fp16 ----------------
__global__ void prep_x(const float* __restrict__ x, unsigned short* __restrict__ xh){
  int i = (blockIdx.x*256 + threadIdx.x)*4;
  float4 v = *(const float4*)(x + i);
  f16x2 a = pkrtz(v.x, v.y), b = pkrtz(v.z, v.w);
  u32x2 u; u.x = __builtin_bit_cast(u32, a); u.y = __builtin_bit_cast(u32, b);
  *(u32x2*)(xh + i) = u;
}

// ---------------- prep: transpose weights to [n][k] fp16 ----------------
__global__ void prep_w(const float* __restrict__ Wq, const float* __restrict__ Wk,
                       const float* __restrict__ Wv, const float* __restrict__ Wp,
                       unsigned short* __restrict__ WT){
  __shared__ float t[64][65];
  const float* W = (blockIdx.z==0)?Wq:(blockIdx.z==1)?Wk:(blockIdx.z==2)?Wv:Wp;
  const int k0 = blockIdx.x*64, n0 = blockIdx.y*64;
  const int c = threadIdx.x&63, rq = threadIdx.x>>6;
  #pragma unroll
  for(int rr=0;rr<16;rr++){
    int kl = rq*16+rr;
    t[kl][c] = W[(size_t)(k0+kl)*DM + n0 + c];
  }
  __syncthreads();
  unsigned short* o = WT + (size_t)blockIdx.z*DM*DM;
  #pragma unroll
  for(int rr=0;rr<16;rr++){
    int nl = rq*16+rr;
    o[(size_t)(n0+nl)*DM + k0 + c] = __builtin_bit_cast(unsigned short, (_Float16)t[c][nl]);
  }
}

// ---------------- QKV projection GEMM (fp16) ----------------
// z=0: Qs (scaled 1/8) [b][h][p][d]; z=1: K [b][h][p][d];
// z=2: VA — V^T A-frag layout [b][g][nt][p/4][d&15][p&3]  (R6-verified layout)
__global__ __launch_bounds__(256) void qkv_kern(const unsigned short* __restrict__ xh,
    const unsigned short* __restrict__ WT,
    unsigned short* __restrict__ Qs, unsigned short* __restrict__ Kk,
    unsigned short* __restrict__ VA){
  const int z = blockIdx.z, h = blockIdx.y;
  const int R0 = blockIdx.x*64;
  const int tid = threadIdx.x;
  const int w = tid>>6, lane = tid&63, m = lane&15, q = lane>>4;
  const unsigned short* Wz = WT + (size_t)z*DM*DM;
  f32x4 acc[4] = {};
  const unsigned short* arow = xh + (size_t)(R0 + w*16 + m)*DM + q*8;
  const unsigned short* brow = Wz + (size_t)(h*64 + m)*DM + q*8;
  for(int k=0;k<DM;k+=32){
    f16x8 A = *(const f16x8*)(arow + k);
    #pragma unroll
    for(int nt=0;nt<4;nt++){
      f16x8 B = *(const f16x8*)(brow + (size_t)nt*16*DM + k);
      acc[nt] = mfma_qk(A, B, acc[nt]);
    }
  }
  __shared__ float t[64][65];
  const float scale = (z==0) ? 0.125f : 1.0f;
  #pragma unroll
  for(int nt=0;nt<4;nt++)
    #pragma unroll
    for(int r=0;r<4;r++)
      t[w*16 + q*4 + r][nt*16 + m] = acc[nt][r]*scale;
  __syncthreads();
  const int b = R0>>11, p0 = R0&2047;
  if(z<2){
    unsigned short* outp = (z==0)? Qs : Kk;
    int pl = tid>>2, c0 = (tid&3)*16;
    u32x4 u0, u1;
    u0.x=__builtin_bit_cast(u32, pkrtz(t[pl][c0+0], t[pl][c0+1]));
    u0.y=__builtin_bit_cast(u32, pkrtz(t[pl][c0+2], t[pl][c0+3]));
    u0.z=__builtin_bit_cast(u32, pkrtz(t[pl][c0+4], t[pl][c0+5]));
    u0.w=__builtin_bit_cast(u32, pkrtz(t[pl][c0+6], t[pl][c0+7]));
    u1.x=__builtin_bit_cast(u32, pkrtz(t[pl][c0+8], t[pl][c0+9]));
    u1.y=__builtin_bit_cast(u32, pkrtz(t[pl][c0+10],t[pl][c0+11]));
    u1.z=__builtin_bit_cast(u32, pkrtz(t[pl][c0+12],t[pl][c0+13]));
    u1.w=__builtin_bit_cast(u32, pkrtz(t[pl][c0+14],t[pl][c0+15]));
    unsigned short* dst = outp + ((size_t)(b*NH+h)*NP + p0+pl)*DH + c0;
    *(u32x4*)dst = u0; *(u32x4*)(dst+8) = u1;
  } else {
    int d = tid>>2, c0 = (tid&3)*16;
    unsigned short* vb = VA + (size_t)b*(8u*4u*(NP/4)*64u)
        + ((size_t)(h*4 + (d>>4))*(NP/4))*64 + (size_t)(d&15)*4;
    #pragma unroll
    for(int grp=0; grp<4; grp++){
      int pl = c0 + grp*4;
      u32x2 u;
      u.x = __builtin_bit_cast(u32, pkrtz(t[pl+0][d], t[pl+1][d]));
      u.y = __builtin_bit_cast(u32, pkrtz(t[pl+2][d], t[pl+3][d]));
      *(u32x2*)(vb + (size_t)((p0 + pl)>>2)*64) = u;
    }
  }
}

// ---------------- attn sweep 1: partial softmax denominators ----------------
// grid order: 64 consecutive blocks share one (b,c) chunk -> L2 locality.
__global__ __launch_bounds__(128,2) void attn1_kern(const unsigned short* __restrict__ Qs,
    const unsigned short* __restrict__ Kk, const float* __restrict__ W1,
    float* __restrict__ Lpart){
  const int bx = blockIdx.x;
  const int it = bx & 63;
  const int pr = bx >> 6;        // 0..15
  const int c = pr & 7;
  const int b = pr >> 3;
  const int tid = threadIdx.x;
  const int iw = tid>>6, lane = tid&63, m = lane&15, q = lane>>4;
  const int i0 = it*32 + iw*16;
  const int cb = c*(NP/JC);

  f16x2 w1f[8][8];
  #pragma unroll
  for(int h=0;h<8;h++)
    #pragma unroll
    for(int g=0;g<8;g++){
      _Float16 v = (_Float16)(W1[h*8+g]*1.44269504f);
      f16x2 p; p[0]=v; p[1]=v; w1f[h][g]=p;
    }

  const unsigned short* Qb = Qs + (size_t)b*NH*NP*DH;
  const unsigned short* Kb = Kk + (size_t)b*NH*NP*DH;

  f16x8 Qf[8][2];
  #pragma unroll
  for(int h=0;h<8;h++){
    const unsigned short* qp = Qb + ((size_t)h*NP + i0 + m)*DH + q*8;
    Qf[h][0] = *(const f16x8*)(qp);
    Qf[h][1] = *(const f16x8*)(qp + 32);
  }

  float lacc[8] = {};
  for(int jt=0; jt<NP/JC/16; jt++){
    const int j0 = cb + jt*16;
    f16x8 K[8][2];
    #pragma unroll
    for(int h=0;h<8;h++){
      const unsigned short* kp = Kb + ((size_t)h*NP + j0 + m)*DH + q*8;
      K[h][0] = *(const f16x8*)(kp);
      K[h][1] = *(const f16x8*)(kp + 32);
    }
    f16x2 shl[8], shh[8];
    #pragma unroll
    for(int h=0;h<8;h++){
      f32x4 z = {};
      z = mfma_qk(K[h][0], Qf[h][0], z);     // A=K (m=j), B=Q (n=i) -> S^T
      f32x4 Sh = mfma_qk(K[h][1], Qf[h][1], z);
      shl[h] = pkrtz(Sh[0], Sh[1]);
      shh[h] = pkrtz(Sh[2], Sh[3]);
    }
    #pragma unroll
    for(int g=0;g<8;g++){
      f16x2 tl = shl[0]*w1f[0][g], th = shh[0]*w1f[0][g];
      #pragma unroll
      for(int h=1;h<8;h++){ tl += shl[h]*w1f[h][g]; th += shh[h]*w1f[h][g]; }
      float e0 = __builtin_amdgcn_exp2f((float)tl[0]);
      float e1 = __builtin_amdgcn_exp2f((float)tl[1]);
      float e2 = __builtin_amdgcn_exp2f((float)th[0]);
      float e3 = __builtin_amdgcn_exp2f((float)th[1]);
      lacc[g] += (e0+e1)+(e2+e3);
    }
  }
  #pragma unroll
  for(int g=0;g<8;g++){
    float v = lacc[g];
    v += __shfl_xor(v,16); v += __shfl_xor(v,32);
    lacc[g] = v;
  }
  if(lane < 16){
    #pragma unroll
    for(int g=0;g<8;g++)
      Lpart[(((size_t)c*NB + b)*NH + g)*NP + i0 + lane] = lacc[g];
  }
}

// ---------------- attn sweep 2: fused QK+mix1+exp2+mix2+PV (pk-f16) -------
// grid order: 64 consecutive blocks share one (b,c) chunk -> L2 locality.
__global__ __launch_bounds__(128,2) void attn2_kern(const unsigned short* __restrict__ Qs,
    const unsigned short* __restrict__ Kk, const unsigned short* __restrict__ VA,
    const float* __restrict__ W1, const float* __restrict__ W2,
    const float* __restrict__ Lpart, unsigned short* __restrict__ Opart){
  const int bx = blockIdx.x;
  const int it = bx & 63;
  const int pr = bx >> 6;        // 0..15
  const int c = pr & 7;
  const int b = pr >> 3;
  const int tid = threadIdx.x;
  const int iw = tid>>6, lane = tid&63, m = lane&15, q = lane>>4;
  const int i0 = it*32 + iw*16;
  const int cb = c*(NP/JC);

  __shared__ unsigned short Osh[32*OPITCH];

  f16x2 w1f[8][8], w2f[8][8];
  #pragma unroll
  for(int h=0;h<8;h++)
    #pragma unroll
    for(int g=0;g<8;g++){
      _Float16 v1 = (_Float16)(W1[h*8+g]*1.44269504f);
      _Float16 v2 = (_Float16)W2[h*8+g];
      f16x2 p1; p1[0]=v1; p1[1]=v1; w1f[h][g]=p1;
      f16x2 p2; p2[0]=v2; p2[1]=v2; w2f[h][g]=p2;
    }

  const unsigned short* Qb = Qs + (size_t)b*NH*NP*DH;
  const unsigned short* Kb = Kk + (size_t)b*NH*NP*DH;
  const unsigned short* VAb = VA + (size_t)b*(8u*4u*(NP/4)*64u);

  // stage this wave's 16 Q rows into its own LDS rows (wave-private, no barrier)
  {
    const int qr = lane>>2, qc = (lane&3)*16;
    #pragma unroll
    for(int h=0;h<8;h++){
      const unsigned short* src = Qb + ((size_t)h*NP + i0 + qr)*DH + qc;
      unsigned short* dst = &Osh[(size_t)(iw*16+qr)*OPITCH + h*64 + qc];
      *(u32x4*)dst = *(const u32x4*)src;
      *(u32x4*)(dst+8) = *(const u32x4*)(src+8);
    }
  }

  // sigma/l per softmax-head g for this lane's i (= i0 + m)
  float rl[8];
  #pragma unroll
  for(int g=0;g<8;g++){
    float v = 0.f;
    #pragma unroll
    for(int cc=0;cc<JC;cc++)
      v += Lpart[(((size_t)cc*NB + b)*NH + g)*NP + i0 + m];
    rl[g] = SIG/v;
  }

  f32x4 Oacc[8][4] = {};
  const unsigned short* QL = &Osh[(size_t)(iw*16+m)*OPITCH];

  for(int jt=0; jt<NP/JC/16; jt++){
    const int j0 = cb + jt*16;
    f16x8 K[8][2];
    #pragma unroll
    for(int h=0;h<8;h++){
      const unsigned short* kp = Kb + ((size_t)h*NP + j0 + m)*DH + q*8;
      K[h][0] = *(const f16x8*)(kp);
      K[h][1] = *(const f16x8*)(kp + 32);
    }
    // V fragments early (latency hidden behind QK+mix+exp)
    f16x4 Vf[8][4];
    const size_t jq = (size_t)(j0>>2) + q;
    #pragma unroll
    for(int g=0;g<8;g++)
      #pragma unroll
      for(int nt=0;nt<4;nt++)
        Vf[g][nt] = *(const f16x4*)(VAb + ((((size_t)g*4+nt)*(NP/4) + jq)<<6) + (m<<2));
    f16x2 shl[8], shh[8];
    #pragma unroll
    for(int h=0;h<8;h++){
      f16x8 q0 = *(const f16x8*)(QL + h*64 + q*8);
      f16x8 q1 = *(const f16x8*)(QL + h*64 + 32 + q*8);
      f32x4 z = {};
      z = mfma_qk(K[h][0], q0, z);
      f32x4 Sh = mfma_qk(K[h][1], q1, z);
      shl[h] = pkrtz(Sh[0], Sh[1]);
      shh[h] = pkrtz(Sh[2], Sh[3]);
    }
    // mix1 (pk) -> exp2 -> normalize+prescale -> P in f16 pairs
    f16x2 plo[8], phi[8];
    #pragma unroll
    for(int g=0;g<8;g++){
      f16x2 tl = shl[0]*w1f[0][g], th = shh[0]*w1f[0][g];
      #pragma unroll
      for(int h=1;h<8;h++){ tl += shl[h]*w1f[h][g]; th += shh[h]*w1f[h][g]; }
      float e0 = __builtin_amdgcn_exp2f((float)tl[0])*rl[g];
      float e1 = __builtin_amdgcn_exp2f((float)tl[1])*rl[g];
      float e2 = __builtin_amdgcn_exp2f((float)th[0])*rl[g];
      float e3 = __builtin_amdgcn_exp2f((float)th[1])*rl[g];
      plo[g] = pkrtz(e0, e1);
      phi[g] = pkrtz(e2, e3);
    }
    // mix2 (pk) -> A2 frag -> PV
    #pragma unroll
    for(int go=0; go<8; go++){
      f16x2 al = plo[0]*w2f[0][go], ah = phi[0]*w2f[0][go];
      #pragma unroll
      for(int h=1;h<8;h++){ al += plo[h]*w2f[h][go]; ah += phi[h]*w2f[h][go]; }
      u32x2 au; au.x = __builtin_bit_cast(u32, al); au.y = __builtin_bit_cast(u32, ah);
      f16x4 A2 = __builtin_bit_cast(f16x4, au);
      #pragma unroll
      for(int nt=0;nt<4;nt++)
        Oacc[go][nt] = mfma_pv(Vf[go][nt], A2, Oacc[go][nt]);
    }
  }

  // epilogue: unscale 1/sigma, wave-private LDS rows, coalesced stores
  #pragma unroll
  for(int g=0;g<8;g++)
    #pragma unroll
    for(int nt=0;nt<4;nt++){
      f32x4 o = Oacc[g][nt];
      u32x2 u;
      u.x = __builtin_bit_cast(u32, pkrtz(o[0]*INVSIG, o[1]*INVSIG));
      u.y = __builtin_bit_cast(u32, pkrtz(o[2]*INVSIG, o[3]*INVSIG));
      *(u32x2*)(&Osh[(size_t)(iw*16 + m)*OPITCH + g*64 + nt*16 + 4*q]) = u;
    }
  __syncthreads();
  unsigned short* Oc = Opart + (size_t)c*NROWS*DM;
  const size_t R0 = (size_t)b*NP + (size_t)it*32;
  #pragma unroll
  for(int t=0;t<16;t++){
    int idx = t*128 + tid;
    int row = idx>>6, c8 = idx&63;
    u32x4 v = *(const u32x4*)(&Osh[(size_t)row*OPITCH + c8*8]);
    *(u32x4*)(Oc + (R0 + row)*DM + c8*8) = v;
  }
}

// ---------------- output projection: out = (sum_c Opart_c) @ Wproj --------
__global__ __launch_bounds__(256) void oproj_kern(const unsigned short* __restrict__ Opart,
    const unsigned short* __restrict__ WT, float* __restrict__ out){
  const int nb = blockIdx.y;
  const int R0 = blockIdx.x*64;
  const int tid = threadIdx.x;
  const int w = tid>>6, lane = tid&63, m = lane&15, q = lane>>4;
  const unsigned short* Wp = WT + (size_t)3*DM*DM;
  f32x4 acc[4] = {};
  const size_t rowoff = (size_t)(R0 + w*16 + m)*DM + q*8;
  const unsigned short* brow = Wp + (size_t)(nb*64 + m)*DM + q*8;
  for(int k=0;k<DM;k+=32){
    f16x8 A = *(const f16x8*)(Opart + rowoff + k);
    #pragma unroll
    for(int cc=1;cc<JC;cc++)
      A += *(const f16x8*)(Opart + (size_t)cc*NROWS*DM + rowoff + k);
    #pragma unroll
    for(int nt=0;nt<4;nt++){
      f16x8 B = *(const f16x8*)(brow + (size_t)nt*16*DM + k);
      acc[nt] = mfma_qk(A, B, acc[nt]);
    }
  }
  #pragma unroll
  for(int nt=0;nt<4;nt++)
    #pragma unroll
    for(int r=0;r<4;r++)
      out[(size_t)(R0 + w*16 + q*4 + r)*DM + nb*64 + nt*16 + m] = acc[nt][r];
}

extern "C" void kernel_launch(void* const* d_in, const int* in_sizes, int n_in,
                              void* d_out, int out_size, void* d_ws, size_t ws_size,
                              hipStream_t stream){
  (void)in_sizes; (void)n_in; (void)out_size; (void)ws_size;
  const float* x  = (const float*)d_in[0];
  const float* Wq = (const float*)d_in[1];
  const float* Wk = (const float*)d_in[2];
  const float* Wv = (const float*)d_in[3];
  const float* W1 = (const float*)d_in[4];
  const float* W2 = (const float*)d_in[5];
  const float* Wp = (const float*)d_in[6];

  char* ws = (char*)d_ws;
  unsigned short* xh = (unsigned short*)ws;  ws += (size_t)NROWS*DM*2;     // 4 MB
  unsigned short* WT = (unsigned short*)ws;  ws += (size_t)4*DM*DM*2;      // 2 MB
  unsigned short* Qs = (unsigned short*)ws;  ws += (size_t)NB*NH*NP*DH*2;  // 4 MB
  unsigned short* Kk = (unsigned short*)ws;  ws += (size_t)NB*NH*NP*DH*2;  // 4 MB
  unsigned short* VA = (unsigned short*)ws;  ws += (size_t)NB*NH*DH*NP*2;  // 4 MB
  float*          Lp = (float*)ws;           ws += (size_t)JC*NB*NH*NP*4;  // 1 MB
  unsigned short* Op = (unsigned short*)ws;  ws += (size_t)JC*NROWS*DM*2;  // 32 MB

  prep_x<<<NROWS*DM/1024, 256, 0, stream>>>(x, xh);
  prep_w<<<dim3(8,8,4), 256, 0, stream>>>(Wq, Wk, Wv, Wp, WT);
  qkv_kern<<<dim3(64,8,3), 256, 0, stream>>>(xh, WT, Qs, Kk, VA);
  attn1_kern<<<dim3(1024), 128, 0, stream>>>(Qs, Kk, W1, Lp);
  attn2_kern<<<dim3(1024), 128, 0, stream>>>(Qs, Kk, VA, W1, W2, Lp, Op);
  oproj_kern<<<dim3(64,8), 256, 0, stream>>>(Op, WT, (float*)d_out);
}